// Round 1
// baseline (109.392 us; speedup 1.0000x reference)
//
#include <hip/hip_runtime.h>
#include <math.h>

#define B 8
#define N 2048
#define DIM 32
#define HID 64
#define ANCHOR 36
#define KLIFT 16
#define DMODEL 256
#define KPROXY 16
#define KSEL 8.0f
#define MT 128

// ---------------- K1: saliency MLP + squared norms ----------------
__global__ __launch_bounds__(256) void k_sal(const float* __restrict__ x,
    const float* __restrict__ W1, const float* __restrict__ b1,
    const float* __restrict__ W2, const float* __restrict__ b2,
    float* __restrict__ sal, float* __restrict__ sq) {
  __shared__ float sW1[DIM * HID];
  __shared__ float sW2[HID], sb1[HID];
  int t = threadIdx.x;
  for (int i = t; i < DIM * HID; i += 256) sW1[i] = W1[i];
  if (t < HID) { sW2[t] = W2[t]; sb1[t] = b1[t]; }
  __syncthreads();
  int p = blockIdx.x * 256 + t;
  float xr[DIM];
  const float4* xp = (const float4*)(x + (size_t)p * DIM);
#pragma unroll
  for (int i = 0; i < DIM / 4; i++) {
    float4 v = xp[i];
    xr[4 * i + 0] = v.x; xr[4 * i + 1] = v.y; xr[4 * i + 2] = v.z; xr[4 * i + 3] = v.w;
  }
  float s = 0.f;
#pragma unroll
  for (int d = 0; d < DIM; d++) s = fmaf(xr[d], xr[d], s);
  sq[p] = s;
  float h[HID];
#pragma unroll
  for (int j = 0; j < HID; j++) h[j] = sb1[j];
  for (int d = 0; d < DIM; d++) {
    float xv = xr[d];
    const float4* wrow = (const float4*)(&sW1[d * HID]);
#pragma unroll
    for (int j4 = 0; j4 < HID / 4; j4++) {
      float4 w = wrow[j4];
      h[4 * j4 + 0] = fmaf(xv, w.x, h[4 * j4 + 0]);
      h[4 * j4 + 1] = fmaf(xv, w.y, h[4 * j4 + 1]);
      h[4 * j4 + 2] = fmaf(xv, w.z, h[4 * j4 + 2]);
      h[4 * j4 + 3] = fmaf(xv, w.w, h[4 * j4 + 3]);
    }
  }
  float acc = b2[0];
#pragma unroll
  for (int j = 0; j < HID; j++) acc = fmaf(fmaxf(h[j], 0.f), sW2[j], acc);
  sal[p] = acc;
}

// ---------------- K2: nearest-neighbor squared distance (row-min) ----------------
// grid = B(8) * ntiles(8) * mchunks(4) = 256 blocks, 256 threads.
// thread: ng = t>>2 owns 4 n's (stride 64), q = t&3 handles m == q (mod 4).
__global__ __launch_bounds__(256) void k_nnd(const float* __restrict__ x,
    const float* __restrict__ sq, unsigned* __restrict__ nnd2) {
  int bid = blockIdx.x;
  int b = bid >> 5;
  int ntile = (bid >> 2) & 7;
  int mchunk = bid & 3;
  int t = threadIdx.x;
  int ng = t >> 2, q = t & 3;
  const float* xb = x + (size_t)b * N * DIM;
  float xn[4][DIM]; float sqn[4]; int nn[4];
#pragma unroll
  for (int i = 0; i < 4; i++) {
    nn[i] = ntile * 256 + ng + 64 * i;
    const float4* p = (const float4*)(xb + (size_t)nn[i] * DIM);
#pragma unroll
    for (int c = 0; c < DIM / 4; c++) {
      float4 v = p[c];
      xn[i][4 * c + 0] = v.x; xn[i][4 * c + 1] = v.y;
      xn[i][4 * c + 2] = v.z; xn[i][4 * c + 3] = v.w;
    }
    sqn[i] = sq[b * N + nn[i]];
  }
  float mn[4] = {1e30f, 1e30f, 1e30f, 1e30f};
  __shared__ float tile[MT * 36];   // padded stride 36 -> conflict-free q-group reads
  __shared__ float stq[MT];
  int m0 = mchunk * 512;
  for (int mb = m0; mb < m0 + 512; mb += MT) {
    __syncthreads();
    {
      int r = t >> 1, hh = t & 1;
      const float4* src = (const float4*)(xb + (size_t)(mb + r) * DIM + hh * 16);
      float4* dst = (float4*)(&tile[r * 36 + hh * 16]);
#pragma unroll
      for (int c = 0; c < 4; c++) dst[c] = src[c];
      if (hh == 0) stq[r] = sq[b * N + mb + r];
    }
    __syncthreads();
    for (int j = 0; j < MT / 4; j++) {
      int mm = j * 4 + q;
      int m = mb + mm;
      const float4* xm4 = (const float4*)(&tile[mm * 36]);
      float xm[DIM];
#pragma unroll
      for (int c = 0; c < DIM / 4; c++) {
        float4 v = xm4[c];
        xm[4 * c + 0] = v.x; xm[4 * c + 1] = v.y; xm[4 * c + 2] = v.z; xm[4 * c + 3] = v.w;
      }
      float d0 = 0.f, d1 = 0.f, d2 = 0.f, d3 = 0.f;
#pragma unroll
      for (int dd = 0; dd < DIM; dd++) {
        float v = xm[dd];
        d0 = fmaf(xn[0][dd], v, d0);
        d1 = fmaf(xn[1][dd], v, d1);
        d2 = fmaf(xn[2][dd], v, d2);
        d3 = fmaf(xn[3][dd], v, d3);
      }
      float sm = stq[mm];
      float v0 = sm - 2.f * d0, v1 = sm - 2.f * d1;
      float v2 = sm - 2.f * d2, v3 = sm - 2.f * d3;
      if (m != nn[0]) mn[0] = fminf(mn[0], v0);
      if (m != nn[1]) mn[1] = fminf(mn[1], v1);
      if (m != nn[2]) mn[2] = fminf(mn[2], v2);
      if (m != nn[3]) mn[3] = fminf(mn[3], v3);
    }
  }
  __shared__ float red[64][4][4];
  __syncthreads();
#pragma unroll
  for (int i = 0; i < 4; i++) red[ng][q][i] = mn[i];
  __syncthreads();
  if (q == 0) {
#pragma unroll
    for (int i = 0; i < 4; i++) {
      float v = fminf(fminf(red[ng][0][i], red[ng][1][i]),
                      fminf(red[ng][2][i], red[ng][3][i]));
      v = fmaxf(sqn[i] + v, 0.f);   // clamp commutes with global min (monotone)
      atomicMin(&nnd2[b * N + nn[i]], __float_as_uint(v));
    }
  }
}

// ---------------- K3: factorized soft selector -> y_star ----------------
// one block per batch, 512 threads, 4 points per thread
__global__ __launch_bounds__(512) void k_select(const float* __restrict__ x,
    const float* __restrict__ sal, const float* __restrict__ sq,
    const unsigned* __restrict__ nnd2, const float* __restrict__ logt,
    float* __restrict__ ystar) {
  int b = blockIdx.x, t = threadIdx.x;
  int lane = t & 63, wid = t >> 6;
  float temp = fminf(fmaxf(expf(logt[0]), 0.1f), 10.f);
  float xr[4][DIM], sl[4], dv[4], nrm[4], y0[4];
#pragma unroll
  for (int i = 0; i < 4; i++) {
    int n = t + 512 * i;
    size_t base = (size_t)(b * N + n);
    const float4* p = (const float4*)(x + base * DIM);
#pragma unroll
    for (int c = 0; c < DIM / 4; c++) {
      float4 v = p[c];
      xr[i][4 * c + 0] = v.x; xr[i][4 * c + 1] = v.y;
      xr[i][4 * c + 2] = v.z; xr[i][4 * c + 3] = v.w;
    }
    sl[i] = sal[base];
    float s = sq[base];
    dv[i] = sqrtf(__uint_as_float(nnd2[base]));
    nrm[i] = sqrtf(s + 3.f * dv[i] * dv[i] + sl[i] * sl[i]) + 1e-8f;
    y0[i] = 1.f / (1.f + expf(-((sl[i] - 0.5f) / temp)));
  }
  // budget 1
  float part = y0[0] + y0[1] + y0[2] + y0[3];
#pragma unroll
  for (int off = 32; off >= 1; off >>= 1) part += __shfl_xor(part, off);
  __shared__ float w1s[8]; __shared__ float bval;
  if (lane == 0) w1s[wid] = part;
  __syncthreads();
  if (t == 0) { float s = 0; for (int w = 0; w < 8; w++) s += w1s[w]; bval = s; }
  __syncthreads();
  float scale1 = fminf(KSEL / fmaxf(bval, 1e-6f), 1.f);
  float y1[4];
#pragma unroll
  for (int i = 0; i < 4; i++) y1[i] = y0[i] * scale1;
  // g = sum_n fhat_n * y1_n  (34 distinct comps: x(32), d, sal)
  float g[34];
  float c0 = y1[0] / nrm[0], c1 = y1[1] / nrm[1];
  float c2 = y1[2] / nrm[2], c3 = y1[3] / nrm[3];
#pragma unroll
  for (int d = 0; d < DIM; d++)
    g[d] = c0 * xr[0][d] + c1 * xr[1][d] + c2 * xr[2][d] + c3 * xr[3][d];
  g[32] = c0 * dv[0] + c1 * dv[1] + c2 * dv[2] + c3 * dv[3];
  g[33] = c0 * sl[0] + c1 * sl[1] + c2 * sl[2] + c3 * sl[3];
#pragma unroll
  for (int k = 0; k < 34; k++) {
    float v = g[k];
#pragma unroll
    for (int off = 32; off >= 1; off >>= 1) v += __shfl_xor(v, off);
    g[k] = v;
  }
  __shared__ float gpart[8][34];
  if (lane == 0) {
#pragma unroll
    for (int k = 0; k < 34; k++) gpart[wid][k] = g[k];
  }
  __syncthreads();
  __shared__ float gfin[34];
  if (t < 34) {
    float s = 0;
    for (int w = 0; w < 8; w++) s += gpart[w][t];
    gfin[t] = s;
  }
  __syncthreads();
  float y2[4];
#pragma unroll
  for (int i = 0; i < 4; i++) {
    float ov = 0.f;
#pragma unroll
    for (int d = 0; d < DIM; d++) ov = fmaf(xr[i][d], gfin[d], ov);
    ov += 3.f * dv[i] * gfin[32] + sl[i] * gfin[33];
    ov /= nrm[i];
    y2[i] = y1[i] / (1.f + ov);
  }
  // budget 2
  float part2 = y2[0] + y2[1] + y2[2] + y2[3];
#pragma unroll
  for (int off = 32; off >= 1; off >>= 1) part2 += __shfl_xor(part2, off);
  __shared__ float w2s[8]; __shared__ float bval2;
  if (lane == 0) w2s[wid] = part2;
  __syncthreads();
  if (t == 0) { float s = 0; for (int w = 0; w < 8; w++) s += w2s[w]; bval2 = s; }
  __syncthreads();
  float scale2 = fminf(KSEL / fmaxf(bval2, 1e-6f), 1.f);
#pragma unroll
  for (int i = 0; i < 4; i++) ystar[b * N + t + 512 * i] = y2[i] * scale2;
}

// ---------------- K4: top-16 with jax tie-breaking (stable, lower index) ----------------
__global__ __launch_bounds__(256) void k_topk(const float* __restrict__ ystar,
                                              int* __restrict__ topidx) {
  int b = blockIdx.x, t = threadIdx.x;
  int lane = t & 63, wid = t >> 6;
  __shared__ float v[N];
  for (int i = t; i < N; i += 256) v[i] = ystar[b * N + i];
  __syncthreads();
  __shared__ float bv[4]; __shared__ int bi[4];
  for (int k = 0; k < KPROXY; k++) {
    float best = -1e30f; int bidx = N;
    for (int i = t; i < N; i += 256) {
      float val = v[i];
      if (val > best || (val == best && i < bidx)) { best = val; bidx = i; }
    }
#pragma unroll
    for (int off = 32; off >= 1; off >>= 1) {
      float ov = __shfl_xor(best, off);
      int oi = __shfl_xor(bidx, off);
      if (ov > best || (ov == best && oi < bidx)) { best = ov; bidx = oi; }
    }
    if (lane == 0) { bv[wid] = best; bi[wid] = bidx; }
    __syncthreads();
    if (t == 0) {
      float fb = bv[0]; int fi = bi[0];
      for (int w = 1; w < 4; w++)
        if (bv[w] > fb || (bv[w] == fb && bi[w] < fi)) { fb = bv[w]; fi = bi[w]; }
      topidx[b * KPROXY + k] = fi;
      v[fi] = -1e30f;
    }
    __syncthreads();
  }
}

// ---------------- K5: lifted (only for selected rows) + token projection ----------------
__global__ __launch_bounds__(256) void k_tokens(const float* __restrict__ x,
    const unsigned* __restrict__ nnd2, const int* __restrict__ topidx,
    const float* __restrict__ mu, const float* __restrict__ sigma,
    const float* __restrict__ Wl, const float* __restrict__ bl,
    const float* __restrict__ Wp, const float* __restrict__ bp,
    float* __restrict__ tok) {
  int bk = blockIdx.x;
  int b = bk >> 4, k = bk & 15;
  int t = threadIdx.x;
  __shared__ float z[ANCHOR]; __shared__ float lift[KLIFT]; __shared__ int srow;
  if (t == 0) srow = topidx[b * KPROXY + k];
  __syncthreads();
  int n = srow;
  if (t < ANCHOR) {
    float dvv;
    if (t < DIM) dvv = x[((size_t)(b * N + n)) * DIM + t];
    else if (t < 35) dvv = sqrtf(__uint_as_float(nnd2[b * N + n]));
    else dvv = 0.f;
    z[t] = (dvv - mu[t]) / sigma[t];
  }
  __syncthreads();
  if (t < KLIFT) {
    float a = bl[t];
#pragma unroll
    for (int d = 0; d < ANCHOR; d++) a = fmaf(z[d], Wl[d * KLIFT + t], a);
    lift[t] = tanhf(a);
  }
  __syncthreads();
  float a = bp[t];
#pragma unroll
  for (int j = 0; j < KLIFT; j++) a = fmaf(lift[j], Wp[j * DMODEL + t], a);
  tok[(size_t)(b * KPROXY + k) * DMODEL + t] = a;
}

extern "C" void kernel_launch(void* const* d_in, const int* in_sizes, int n_in,
                              void* d_out, int out_size, void* d_ws, size_t ws_size,
                              hipStream_t stream) {
  const float* x  = (const float*)d_in[0];
  const float* lt = (const float*)d_in[1];
  const float* W1 = (const float*)d_in[2];
  const float* b1 = (const float*)d_in[3];
  const float* W2 = (const float*)d_in[4];
  const float* b2 = (const float*)d_in[5];
  const float* mu = (const float*)d_in[6];
  const float* sg = (const float*)d_in[7];
  const float* Wl = (const float*)d_in[8];
  const float* bl = (const float*)d_in[9];
  const float* Wp = (const float*)d_in[10];
  const float* bp = (const float*)d_in[11];

  float* tok = (float*)d_out;
  float* ystar = tok + B * KPROXY * DMODEL;   // out = [tokens(32768), y_star(16384)]

  char* ws = (char*)d_ws;
  float* sal      = (float*)(ws);             // 16384 f
  float* sq       = (float*)(ws + 65536);     // 16384 f
  unsigned* nnd2  = (unsigned*)(ws + 131072); // 16384 u32 (float bits, >=0)
  int* topidx     = (int*)(ws + 196608);      // 128 i32

  hipMemsetAsync(nnd2, 0x7F, B * N * sizeof(unsigned), stream); // 0x7F7F7F7F = huge float
  k_sal<<<B * N / 256, 256, 0, stream>>>(x, W1, b1, W2, b2, sal, sq);
  k_nnd<<<256, 256, 0, stream>>>(x, sq, nnd2);
  k_select<<<B, 512, 0, stream>>>(x, sal, sq, nnd2, lt, ystar);
  k_topk<<<B, 256, 0, stream>>>(ystar, topidx);
  k_tokens<<<B * KPROXY, 256, 0, stream>>>(x, nnd2, topidx, mu, sg, Wl, bl, Wp, bp, tok);
}

// Round 2
// 64.408 us; speedup vs baseline: 1.6984x; 1.6984x over previous
//
#include <hip/hip_runtime.h>
#include <math.h>

#define B 8
#define N 2048
#define DIM 32
#define HID 64
#define KLIFT 16
#define DMODEL 256
#define KPROXY 16
#define KSEL 8.0f

typedef float f32x4 __attribute__((ext_vector_type(4)));
typedef short bf16x8 __attribute__((ext_vector_type(8)));

__device__ inline unsigned short f2bf(float f) {
  unsigned u = __float_as_uint(f);
  unsigned r = (u + 0x7FFFu + ((u >> 16) & 1u)) >> 16;  // RNE
  return (unsigned short)r;
}
__device__ inline float bf2f(unsigned short s) {
  return __uint_as_float(((unsigned)s) << 16);
}

// ---------------- K1: saliency MLP + sq-norm + bf16 hi/lo split (fragment order) + nnd2 init
__global__ __launch_bounds__(64) void k_prep(
    const float* __restrict__ x, const float* __restrict__ W1,
    const float* __restrict__ b1, const float* __restrict__ W2,
    const float* __restrict__ b2, float* __restrict__ sal,
    float* __restrict__ sq, unsigned short* __restrict__ Xhi,
    unsigned short* __restrict__ Xlo, unsigned* __restrict__ nnd2) {
  __shared__ float sW1[DIM * HID];
  __shared__ float sW2[HID], sb1[HID];
  int t = threadIdx.x;
  {
    const float4* s4 = (const float4*)W1;
    float4* d4 = (float4*)sW1;
    for (int i = t; i < DIM * HID / 4; i += 64) d4[i] = s4[i];
    sW2[t] = W2[t]; sb1[t] = b1[t];   // t < 64 == HID
  }
  __syncthreads();
  int p = blockIdx.x * 64 + t;        // 0..16383
  nnd2[p] = 0x7F7F7F7Fu;              // huge positive float bits
  float xr[DIM];
  const float4* xp = (const float4*)(x + (size_t)p * DIM);
#pragma unroll
  for (int i = 0; i < DIM / 4; i++) {
    float4 v = xp[i];
    xr[4 * i + 0] = v.x; xr[4 * i + 1] = v.y; xr[4 * i + 2] = v.z; xr[4 * i + 3] = v.w;
  }
  float s = 0.f;
#pragma unroll
  for (int d = 0; d < DIM; d++) s = fmaf(xr[d], xr[d], s);
  sq[p] = s;
  float h[HID];
#pragma unroll
  for (int j = 0; j < HID; j++) h[j] = sb1[j];
  for (int d = 0; d < DIM; d++) {
    float xv = xr[d];
    const float4* wrow = (const float4*)(&sW1[d * HID]);
#pragma unroll
    for (int j4 = 0; j4 < HID / 4; j4++) {
      float4 w = wrow[j4];
      h[4 * j4 + 0] = fmaf(xv, w.x, h[4 * j4 + 0]);
      h[4 * j4 + 1] = fmaf(xv, w.y, h[4 * j4 + 1]);
      h[4 * j4 + 2] = fmaf(xv, w.z, h[4 * j4 + 2]);
      h[4 * j4 + 3] = fmaf(xv, w.w, h[4 * j4 + 3]);
    }
  }
  float acc = b2[0];
#pragma unroll
  for (int j = 0; j < HID; j++) acc = fmaf(fmaxf(h[j], 0.f), sW2[j], acc);
  sal[p] = acc;
  // fragment-order bf16 split: lane L = g*16+c of tile holds X[tile*16+c][g*8+j]
  int bb = p >> 11, n = p & (N - 1);
  int tile = n >> 4, c = n & 15;
  size_t tb = ((size_t)(bb * 128 + tile)) * 64;
#pragma unroll
  for (int g = 0; g < 4; g++) {
    bf16x8 hv, lv;
#pragma unroll
    for (int j = 0; j < 8; j++) {
      float v = xr[g * 8 + j];
      unsigned short hb = f2bf(v);
      hv[j] = (short)hb;
      lv[j] = (short)f2bf(v - bf2f(hb));
    }
    size_t off = (tb + (size_t)g * 16 + c) * 8;
    *(bf16x8*)(Xhi + off) = hv;
    *(bf16x8*)(Xlo + off) = lv;
  }
}

// ---------------- K2: NN squared distance via split-bf16 MFMA Gram ----------------
// grid = 8 b * 16 nchunks(128 rows) * 4 mquarters(512 rows) = 512 blocks, 4 waves.
// wave owns 2 n-tiles (32 rows); block stages its whole m-quarter (32 tiles) in LDS.
__global__ __launch_bounds__(256) void k_nnd(
    const unsigned short* __restrict__ Xhi, const unsigned short* __restrict__ Xlo,
    const float* __restrict__ sq, unsigned* __restrict__ nnd2) {
  int bid = blockIdx.x;
  int bb = bid >> 6;
  int nch = (bid >> 2) & 15;
  int mq = bid & 3;
  int t = threadIdx.x;
  int w = t >> 6, lane = t & 63;
  int c = lane & 15, g = lane >> 4;
  __shared__ unsigned short ldsH[32 * 512];  // 32 m-tiles, frag order (32 KB)
  __shared__ unsigned short ldsL[32 * 512];
  __shared__ float ssq[512];
  // stage m-quarter: linear copy (frag order == linear)
  {
    size_t base = ((size_t)(bb * 128 + mq * 32)) * 512;
    const float4* srcH = (const float4*)(Xhi + base);
    const float4* srcL = (const float4*)(Xlo + base);
    float4* dH = (float4*)ldsH;
    float4* dL = (float4*)ldsL;
    for (int i = t; i < 32 * 512 / 8; i += 256) { dH[i] = srcH[i]; dL[i] = srcL[i]; }
    ssq[t] = sq[bb * N + mq * 512 + t];
    ssq[t + 256] = sq[bb * N + mq * 512 + t + 256];
  }
  int nt0 = nch * 8 + w * 2, nt1 = nt0 + 1;
  bf16x8 ah0 = *(const bf16x8*)(Xhi + (((size_t)(bb * 128 + nt0)) * 64 + lane) * 8);
  bf16x8 al0 = *(const bf16x8*)(Xlo + (((size_t)(bb * 128 + nt0)) * 64 + lane) * 8);
  bf16x8 ah1 = *(const bf16x8*)(Xhi + (((size_t)(bb * 128 + nt1)) * 64 + lane) * 8);
  bf16x8 al1 = *(const bf16x8*)(Xlo + (((size_t)(bb * 128 + nt1)) * 64 + lane) * 8);
  __syncthreads();
  float mn0[4] = {1e30f, 1e30f, 1e30f, 1e30f};
  float mn1[4] = {1e30f, 1e30f, 1e30f, 1e30f};
  for (int tt = 0; tt < 32; tt++) {
    bf16x8 bh = ((const bf16x8*)(ldsH + tt * 512))[lane];
    bf16x8 bl2 = ((const bf16x8*)(ldsL + tt * 512))[lane];
    f32x4 a0 = {0.f, 0.f, 0.f, 0.f};
    f32x4 a1 = {0.f, 0.f, 0.f, 0.f};
    a0 = __builtin_amdgcn_mfma_f32_16x16x32_bf16(ah0, bh, a0, 0, 0, 0);
    a1 = __builtin_amdgcn_mfma_f32_16x16x32_bf16(ah1, bh, a1, 0, 0, 0);
    a0 = __builtin_amdgcn_mfma_f32_16x16x32_bf16(ah0, bl2, a0, 0, 0, 0);
    a1 = __builtin_amdgcn_mfma_f32_16x16x32_bf16(ah1, bl2, a1, 0, 0, 0);
    a0 = __builtin_amdgcn_mfma_f32_16x16x32_bf16(al0, bh, a0, 0, 0, 0);
    a1 = __builtin_amdgcn_mfma_f32_16x16x32_bf16(al1, bh, a1, 0, 0, 0);
    float sm = ssq[tt * 16 + c];
    int mtg = mq * 32 + tt;
    bool d0 = (mtg == nt0), d1 = (mtg == nt1);
#pragma unroll
    for (int r = 0; r < 4; r++) {
      float v0 = fmaf(-2.f, a0[r], sm);
      float v1 = fmaf(-2.f, a1[r], sm);
      if (d0 && c == 4 * g + r) v0 = 1e30f;   // mask self-distance
      if (d1 && c == 4 * g + r) v1 = 1e30f;
      mn0[r] = fminf(mn0[r], v0);
      mn1[r] = fminf(mn1[r], v1);
    }
  }
#pragma unroll
  for (int off = 1; off <= 8; off <<= 1) {
#pragma unroll
    for (int r = 0; r < 4; r++) {
      mn0[r] = fminf(mn0[r], __shfl_xor(mn0[r], off));
      mn1[r] = fminf(mn1[r], __shfl_xor(mn1[r], off));
    }
  }
  if (c == 0) {
#pragma unroll
    for (int r = 0; r < 4; r++) {
      int n0 = nt0 * 16 + 4 * g + r;
      float v = fmaxf(sq[bb * N + n0] + mn0[r], 0.f);
      atomicMin(&nnd2[bb * N + n0], __float_as_uint(v));
      int n1 = nt1 * 16 + 4 * g + r;
      v = fmaxf(sq[bb * N + n1] + mn1[r], 0.f);
      atomicMin(&nnd2[bb * N + n1], __float_as_uint(v));
    }
  }
}

// ---------------- K3: fused selector + top-16 + token projection ----------------
__global__ __launch_bounds__(512) void k_post(
    const float* __restrict__ x, const float* __restrict__ sal,
    const float* __restrict__ sq, const unsigned* __restrict__ nnd2,
    const float* __restrict__ logt, const float* __restrict__ mu,
    const float* __restrict__ sigma, const float* __restrict__ Wl,
    const float* __restrict__ bl, const float* __restrict__ Wp,
    const float* __restrict__ bp, float* __restrict__ tok,
    float* __restrict__ ystar) {
  int b = blockIdx.x, t = threadIdx.x;
  int lane = t & 63, wid = t >> 6;
  __shared__ float yv[N];
  __shared__ float red[8];
  __shared__ float gpart[8][34];
  __shared__ float gfin[34];
  __shared__ float bsh[2];
  __shared__ float candv[128];
  __shared__ int candi[128];
  __shared__ int tix[KPROXY];
  __shared__ float sz[KPROXY][36];

  float temp = fminf(fmaxf(expf(logt[0]), 0.1f), 10.f);
  float xr[4][DIM], sl[4], dv[4], nrm[4], y0[4];
#pragma unroll
  for (int i = 0; i < 4; i++) {
    int n = t + 512 * i;
    size_t base = (size_t)b * N + n;
    const float4* p4 = (const float4*)(x + base * DIM);
#pragma unroll
    for (int cc = 0; cc < 8; cc++) {
      float4 v = p4[cc];
      xr[i][4 * cc + 0] = v.x; xr[i][4 * cc + 1] = v.y;
      xr[i][4 * cc + 2] = v.z; xr[i][4 * cc + 3] = v.w;
    }
    sl[i] = sal[base];
    dv[i] = sqrtf(__uint_as_float(nnd2[base]));
    nrm[i] = sqrtf(sq[base] + 3.f * dv[i] * dv[i] + sl[i] * sl[i]) + 1e-8f;
    y0[i] = 1.f / (1.f + expf(-((sl[i] - 0.5f) / temp)));
  }
  // budget 1
  float part = y0[0] + y0[1] + y0[2] + y0[3];
#pragma unroll
  for (int off = 32; off >= 1; off >>= 1) part += __shfl_xor(part, off);
  if (lane == 0) red[wid] = part;
  __syncthreads();
  if (t == 0) { float s = 0; for (int ww = 0; ww < 8; ww++) s += red[ww]; bsh[0] = s; }
  __syncthreads();
  float scale1 = fminf(KSEL / fmaxf(bsh[0], 1e-6f), 1.f);
  float y1[4];
#pragma unroll
  for (int i = 0; i < 4; i++) y1[i] = y0[i] * scale1;
  // g = sum fhat * y1  (34 comps: x(32), d, sal; d appears 3x in features)
  float gg[34];
  float c0 = y1[0] / nrm[0], c1 = y1[1] / nrm[1];
  float c2 = y1[2] / nrm[2], c3 = y1[3] / nrm[3];
#pragma unroll
  for (int d = 0; d < DIM; d++)
    gg[d] = c0 * xr[0][d] + c1 * xr[1][d] + c2 * xr[2][d] + c3 * xr[3][d];
  gg[32] = c0 * dv[0] + c1 * dv[1] + c2 * dv[2] + c3 * dv[3];
  gg[33] = c0 * sl[0] + c1 * sl[1] + c2 * sl[2] + c3 * sl[3];
#pragma unroll
  for (int k2 = 0; k2 < 34; k2++) {
    float v = gg[k2];
#pragma unroll
    for (int off = 32; off >= 1; off >>= 1) v += __shfl_xor(v, off);
    gg[k2] = v;
  }
  if (lane == 0) {
#pragma unroll
    for (int k2 = 0; k2 < 34; k2++) gpart[wid][k2] = gg[k2];
  }
  __syncthreads();
  if (t < 34) {
    float s = 0;
    for (int ww = 0; ww < 8; ww++) s += gpart[ww][t];
    gfin[t] = s;
  }
  __syncthreads();
  float y2[4];
#pragma unroll
  for (int i = 0; i < 4; i++) {
    float ov = 0.f;
#pragma unroll
    for (int d = 0; d < DIM; d++) ov = fmaf(xr[i][d], gfin[d], ov);
    ov += 3.f * dv[i] * gfin[32] + sl[i] * gfin[33];
    ov /= nrm[i];
    y2[i] = y1[i] / (1.f + ov);
  }
  // budget 2
  float part2 = y2[0] + y2[1] + y2[2] + y2[3];
#pragma unroll
  for (int off = 32; off >= 1; off >>= 1) part2 += __shfl_xor(part2, off);
  if (lane == 0) red[wid] = part2;
  __syncthreads();
  if (t == 0) { float s = 0; for (int ww = 0; ww < 8; ww++) s += red[ww]; bsh[1] = s; }
  __syncthreads();
  float scale2 = fminf(KSEL / fmaxf(bsh[1], 1e-6f), 1.f);
#pragma unroll
  for (int i = 0; i < 4; i++) {
    int n = t + 512 * i;
    float ys = y2[i] * scale2;
    yv[n] = ys;
    ystar[(size_t)b * N + n] = ys;
  }
  __syncthreads();
  // ---- top-16 stage 1: per-wave top-16 of its 256 elems (ties -> lower index) ----
  float lv0 = yv[wid * 256 + lane];        int li0 = wid * 256 + lane;
  float lv1 = yv[wid * 256 + 64 + lane];   int li1 = li0 + 64;
  float lv2 = yv[wid * 256 + 128 + lane];  int li2 = li0 + 128;
  float lv3 = yv[wid * 256 + 192 + lane];  int li3 = li0 + 192;
  for (int r = 0; r < KPROXY; r++) {
    float bv = lv0; int bi = li0;
    if (lv1 > bv) { bv = lv1; bi = li1; }
    if (lv2 > bv) { bv = lv2; bi = li2; }
    if (lv3 > bv) { bv = lv3; bi = li3; }
#pragma unroll
    for (int off = 1; off < 64; off <<= 1) {
      float ovv = __shfl_xor(bv, off);
      int oi = __shfl_xor(bi, off);
      if (ovv > bv || (ovv == bv && oi < bi)) { bv = ovv; bi = oi; }
    }
    if (lane == 0) { candv[wid * 16 + r] = bv; candi[wid * 16 + r] = bi; }
    if (li0 == bi) lv0 = -1e30f;
    if (li1 == bi) lv1 = -1e30f;
    if (li2 == bi) lv2 = -1e30f;
    if (li3 == bi) lv3 = -1e30f;
  }
  __syncthreads();
  // ---- stage 2: wave 0 merges 128 candidates ----
  if (wid == 0) {
    float cv0 = candv[lane], cv1 = candv[lane + 64];
    int ci0 = candi[lane], ci1 = candi[lane + 64];
    for (int r = 0; r < KPROXY; r++) {
      float bv = cv0; int bi = ci0;
      if (cv1 > bv || (cv1 == bv && ci1 < bi)) { bv = cv1; bi = ci1; }
#pragma unroll
      for (int off = 1; off < 64; off <<= 1) {
        float ovv = __shfl_xor(bv, off);
        int oi = __shfl_xor(bi, off);
        if (ovv > bv || (ovv == bv && oi < bi)) { bv = ovv; bi = oi; }
      }
      if (lane == 0) tix[r] = bi;
      if (ci0 == bi) cv0 = -1e30f;
      if (ci1 == bi) cv1 = -1e30f;
    }
  }
  __syncthreads();
  // ---- tokens: one wave per selected row, 2 rounds ----
  for (int it = 0; it < 2; it++) {
    int k = wid + 8 * it;
    int srow = tix[k];
    if (lane < 36) {
      float f;
      if (lane < 32) f = x[((size_t)b * N + srow) * DIM + lane];
      else if (lane < 35) f = sqrtf(__uint_as_float(nnd2[b * N + srow]));
      else f = 0.f;   // std of single NN distance is exactly 0
      sz[k][lane] = (f - mu[lane]) / sigma[lane];
    }
    __syncthreads();
    float lf = 0.f;
    if (lane < KLIFT) {
      float a = bl[lane];
#pragma unroll
      for (int d = 0; d < 36; d++) a = fmaf(sz[k][d], Wl[d * KLIFT + lane], a);
      lf = tanhf(a);
    }
    float o0 = bp[lane], o1 = bp[lane + 64], o2 = bp[lane + 128], o3 = bp[lane + 192];
#pragma unroll
    for (int j = 0; j < KLIFT; j++) {
      float lj = __shfl(lf, j);
      const float* wr = Wp + j * DMODEL + lane;
      o0 = fmaf(lj, wr[0], o0);
      o1 = fmaf(lj, wr[64], o1);
      o2 = fmaf(lj, wr[128], o2);
      o3 = fmaf(lj, wr[192], o3);
    }
    float* tp = tok + ((size_t)b * KPROXY + k) * DMODEL + lane;
    tp[0] = o0; tp[64] = o1; tp[128] = o2; tp[192] = o3;
  }
}

extern "C" void kernel_launch(void* const* d_in, const int* in_sizes, int n_in,
                              void* d_out, int out_size, void* d_ws, size_t ws_size,
                              hipStream_t stream) {
  const float* x  = (const float*)d_in[0];
  const float* lt = (const float*)d_in[1];
  const float* W1 = (const float*)d_in[2];
  const float* b1 = (const float*)d_in[3];
  const float* W2 = (const float*)d_in[4];
  const float* b2 = (const float*)d_in[5];
  const float* mu = (const float*)d_in[6];
  const float* sg = (const float*)d_in[7];
  const float* Wl = (const float*)d_in[8];
  const float* bl = (const float*)d_in[9];
  const float* Wp = (const float*)d_in[10];
  const float* bp = (const float*)d_in[11];

  float* tok = (float*)d_out;
  float* ystar = tok + B * KPROXY * DMODEL;

  char* ws = (char*)d_ws;
  float* sal           = (float*)(ws);                 // 64 KB
  float* sq            = (float*)(ws + 65536);         // 64 KB
  unsigned* nnd2       = (unsigned*)(ws + 131072);     // 64 KB
  unsigned short* Xhi  = (unsigned short*)(ws + 196608);   // 1 MB
  unsigned short* Xlo  = (unsigned short*)(ws + 196608 + 1048576); // 1 MB

  k_prep<<<B * N / 64, 64, 0, stream>>>(x, W1, b1, W2, b2, sal, sq, Xhi, Xlo, nnd2);
  k_nnd<<<512, 256, 0, stream>>>(Xhi, Xlo, sq, nnd2);
  k_post<<<B, 512, 0, stream>>>(x, sal, sq, nnd2, lt, mu, sg, Wl, bl, Wp, bp, tok, ystar);
}